// Round 1
// baseline (421.189 us; speedup 1.0000x reference)
//
#include <hip/hip_runtime.h>

#define TX 64
#define TY 16
#define HR (TY + 10)   // 26 rows of horizontally-blurred data
#define IW (TX + 10)   // 74 staged input columns
#define HSTR 66        // padded stride for H buffer (bank-conflict-free)
#define IMW 512
#define IMH 512
#define NPLANES 96     // 32 * 3
#define NBX (IMW / TX) // 8
#define NBY (IMH / TY) // 32
#define NBLOCKS (NBX * NBY * NPLANES) // 24576

__device__ __forceinline__ void gauss_weights(float* w) {
  double t[11];
  double s = 0.0;
#pragma unroll
  for (int i = 0; i < 11; ++i) {
    double d = (double)(i - 5);
    t[i] = exp(-d * d / 4.5);  // 2*sigma^2 = 4.5
    s += t[i];
  }
#pragma unroll
  for (int i = 0; i < 11; ++i) w[i] = (float)(t[i] / s);
}

__global__ __launch_bounds__(256, 3) void ssim_main(
    const float* __restrict__ gen, const float* __restrict__ ref,
    float* __restrict__ partial) {
  __shared__ float sg[HR][IW];
  __shared__ float sr[HR][IW];
  __shared__ float sh[5][HR][HSTR];
  __shared__ float swsum[4];

  const int tid = threadIdx.x;
  const int bid = blockIdx.x;
  const int bx = bid % NBX;
  const int by = (bid / NBX) % NBY;
  const int plane = bid / (NBX * NBY);
  const int x0 = bx * TX;
  const int y0 = by * TY;
  const float* gp = gen + (size_t)plane * (IMW * IMH);
  const float* rp = ref + (size_t)plane * (IMW * IMH);

  float w[11];
  gauss_weights(w);

  // Stage transformed inputs ((x+1)*0.5), zero outside the image (zero-pad conv).
  for (int i = tid; i < HR * IW; i += 256) {
    int r = i / IW;
    int c = i - r * IW;
    int gy = y0 - 5 + r;
    int gx = x0 - 5 + c;
    float vg = 0.f, vr = 0.f;
    if (gy >= 0 && gy < IMH && gx >= 0 && gx < IMW) {
      int idx = gy * IMW + gx;
      vg = fmaf(0.5f, gp[idx], 0.5f);
      vr = fmaf(0.5f, rp[idx], 0.5f);
    }
    sg[r][c] = vg;
    sr[r][c] = vr;
  }
  __syncthreads();

  // Phase 1: horizontal 11-tap blur of 5 quantities (g, r, gg, rr, gr).
  // 208 threads: each handles one row-run of 8 consecutive outputs.
  if (tid < HR * 8) {
    const int row = tid >> 3;
    const int xs = (tid & 7) * 8;
    float vg[18], vr[18], vgg[18], vrr[18], vgr[18];
#pragma unroll
    for (int j = 0; j < 18; ++j) {
      float g = sg[row][xs + j];
      float r = sr[row][xs + j];
      vg[j] = g;
      vr[j] = r;
      vgg[j] = g * g;
      vrr[j] = r * r;
      vgr[j] = g * r;
    }
#pragma unroll
    for (int o = 0; o < 8; ++o) {
      float s0 = 0.f, s1 = 0.f, s2 = 0.f, s3 = 0.f, s4 = 0.f;
#pragma unroll
      for (int t = 0; t < 11; ++t) {
        float wt = w[t];
        s0 = fmaf(wt, vg[o + t], s0);
        s1 = fmaf(wt, vr[o + t], s1);
        s2 = fmaf(wt, vgg[o + t], s2);
        s3 = fmaf(wt, vrr[o + t], s3);
        s4 = fmaf(wt, vgr[o + t], s4);
      }
      sh[0][row][xs + o] = s0;
      sh[1][row][xs + o] = s1;
      sh[2][row][xs + o] = s2;
      sh[3][row][xs + o] = s3;
      sh[4][row][xs + o] = s4;
    }
  }
  __syncthreads();

  // Phase 2: vertical 11-tap blur + SSIM. 64 cols x 4 row-groups x 4 outputs.
  const int col = tid & 63;
  const int r0 = (tid >> 6) * 4;
  float hv[5][14];
#pragma unroll
  for (int q = 0; q < 5; ++q) {
#pragma unroll
    for (int i = 0; i < 14; ++i) hv[q][i] = sh[q][r0 + i][col];
  }

  const float C1 = 6.5025f, C2 = 58.5225f;
  float lsum = 0.f;
#pragma unroll
  for (int o = 0; o < 4; ++o) {
    float mu1 = 0.f, mu2 = 0.f, e1 = 0.f, e2 = 0.f, e12 = 0.f;
#pragma unroll
    for (int t = 0; t < 11; ++t) {
      float wt = w[t];
      mu1 = fmaf(wt, hv[0][o + t], mu1);
      mu2 = fmaf(wt, hv[1][o + t], mu2);
      e1 = fmaf(wt, hv[2][o + t], e1);
      e2 = fmaf(wt, hv[3][o + t], e2);
      e12 = fmaf(wt, hv[4][o + t], e12);
    }
    float m12 = mu1 * mu2;
    float m1s = mu1 * mu1;
    float m2s = mu2 * mu2;
    float num = (2.f * m12 + C1) * (2.f * (e12 - m12) + C2);
    float den = (m1s + m2s + C1) * ((e1 - m1s) + (e2 - m2s) + C2);
    lsum += num / den;
  }

  // Block reduction -> one partial per block (deterministic, no atomics).
#pragma unroll
  for (int off = 32; off > 0; off >>= 1) lsum += __shfl_down(lsum, off, 64);
  if ((tid & 63) == 0) swsum[tid >> 6] = lsum;
  __syncthreads();
  if (tid == 0) partial[bid] = swsum[0] + swsum[1] + swsum[2] + swsum[3];
}

__global__ void ssim_reduce(const float* __restrict__ partial,
                            float* __restrict__ out) {
  double s = 0.0;
  for (int i = threadIdx.x; i < NBLOCKS; i += 256) s += (double)partial[i];
#pragma unroll
  for (int off = 32; off > 0; off >>= 1) s += __shfl_down(s, off, 64);
  __shared__ double sd[4];
  if ((threadIdx.x & 63) == 0) sd[threadIdx.x >> 6] = s;
  __syncthreads();
  if (threadIdx.x == 0) {
    double npix = (double)NPLANES * (double)IMW * (double)IMH;
    out[0] = (float)(1.0 - (sd[0] + sd[1] + sd[2] + sd[3]) / npix);
  }
}

extern "C" void kernel_launch(void* const* d_in, const int* in_sizes, int n_in,
                              void* d_out, int out_size, void* d_ws, size_t ws_size,
                              hipStream_t stream) {
  (void)in_sizes; (void)n_in; (void)out_size; (void)ws_size;
  const float* gen = (const float*)d_in[0];
  const float* ref = (const float*)d_in[1];
  float* partial = (float*)d_ws;  // NBLOCKS floats; every slot written each call
  ssim_main<<<NBLOCKS, 256, 0, stream>>>(gen, ref, partial);
  ssim_reduce<<<1, 256, 0, stream>>>(partial, (float*)d_out);
}

// Round 2
// 310.496 us; speedup vs baseline: 1.3565x; 1.3565x over previous
//
#include <hip/hip_runtime.h>

#define TX 64
#define TY 20
#define PROWS (TY + 10)            // 30 rows of h-blurred data per tile
#define HSTR 67                    // LDS stride: 67%32=3 (odd) -> <=2-way, free
#define IMW 512
#define IMH 512
#define NPLANES 96                 // 32 * 3
#define NBX (IMW / TX)             // 8
#define NBY ((IMH + TY - 1) / TY)  // 26 (last tile covers 12 valid rows)
#define NBLOCKS (NBX * NBY * NPLANES)  // 19968

__device__ __forceinline__ float uniform_f(float v) {
  // force wave-uniform value into an SGPR
  return __int_as_float(__builtin_amdgcn_readfirstlane(__float_as_int(v)));
}

__device__ __forceinline__ void gauss_weights(float* w) {
  double t[11];
  double s = 0.0;
#pragma unroll
  for (int i = 0; i < 11; ++i) {
    double d = (double)(i - 5);
    t[i] = exp(-d * d / 4.5);  // 2*sigma^2 = 4.5
    s += t[i];
  }
#pragma unroll
  for (int i = 0; i < 11; ++i) w[i] = uniform_f((float)(t[i] / s));
}

__global__ __launch_bounds__(256, 4) void ssim_main(
    const float* __restrict__ gen, const float* __restrict__ ref,
    float* __restrict__ partial) {
  __shared__ float sh[5][PROWS][HSTR];  // 40,200 B
  __shared__ float swsum[4];

  const int tid = threadIdx.x;
  const int bid = blockIdx.x;
  const int rem = bid % (NBX * NBY);
  const int plane = bid / (NBX * NBY);
  const int bx = rem % NBX;
  const int by = rem / NBX;
  const int x0 = bx * TX;
  const int y0 = by * TY;
  const float* gp = gen + (size_t)plane * (IMW * IMH);
  const float* rp = ref + (size_t)plane * (IMW * IMH);

  float w[11];
  gauss_weights(w);

  // ---- Phase 1: horizontal 11-tap blur of 5 quantities, read from GLOBAL.
  // 240 threads: (row 0..29) x (8 runs of 8 outputs). Window = 24 floats
  // loaded as 6 aligned float4 (whole-vec in/out of image; IMW%4==0).
  if (tid < PROWS * 8) {
    const int row = tid >> 3;
    const int xs = (tid & 7) * 8;
    const int gy = y0 - 5 + row;
    const bool rowok = (gy >= 0) && (gy < IMH);
    const int xbase = x0 + xs - 8;  // window cols [xbase, xbase+24)
    const float* grow = gp + (size_t)gy * IMW;
    const float* rrow = rp + (size_t)gy * IMW;

    float ga[24], ra[24];
#pragma unroll
    for (int k = 0; k < 6; ++k) {
      const int c = xbase + 4 * k;
      const bool ok = rowok && (c >= 0) && (c < IMW);
      float4 vg = make_float4(0.f, 0.f, 0.f, 0.f);
      float4 vr = make_float4(0.f, 0.f, 0.f, 0.f);
      if (ok) {
        float4 g4 = *(const float4*)(grow + c);
        float4 r4 = *(const float4*)(rrow + c);
        vg.x = fmaf(0.5f, g4.x, 0.5f); vg.y = fmaf(0.5f, g4.y, 0.5f);
        vg.z = fmaf(0.5f, g4.z, 0.5f); vg.w = fmaf(0.5f, g4.w, 0.5f);
        vr.x = fmaf(0.5f, r4.x, 0.5f); vr.y = fmaf(0.5f, r4.y, 0.5f);
        vr.z = fmaf(0.5f, r4.z, 0.5f); vr.w = fmaf(0.5f, r4.w, 0.5f);
      }
      ga[4 * k + 0] = vg.x; ga[4 * k + 1] = vg.y;
      ga[4 * k + 2] = vg.z; ga[4 * k + 3] = vg.w;
      ra[4 * k + 0] = vr.x; ra[4 * k + 1] = vr.y;
      ra[4 * k + 2] = vr.z; ra[4 * k + 3] = vr.w;
    }

    float acc[5][8];
#pragma unroll
    for (int q = 0; q < 5; ++q)
#pragma unroll
      for (int o = 0; o < 8; ++o) acc[q][o] = 0.f;

#pragma unroll
    for (int p = 0; p < 18; ++p) {   // window position; col = X-5+p = ga[p+3]
      const float g = ga[p + 3];
      const float r = ra[p + 3];
      const float gg = g * g;
      const float rr = r * r;
      const float gr = g * r;
      const int olo = (p - 10 < 0) ? 0 : p - 10;
      const int ohi = (p < 7) ? p : 7;
#pragma unroll
      for (int o = olo; o <= ohi; ++o) {
        const float wt = w[p - o];
        acc[0][o] = fmaf(wt, g, acc[0][o]);
        acc[1][o] = fmaf(wt, r, acc[1][o]);
        acc[2][o] = fmaf(wt, gg, acc[2][o]);
        acc[3][o] = fmaf(wt, rr, acc[3][o]);
        acc[4][o] = fmaf(wt, gr, acc[4][o]);
      }
    }
#pragma unroll
    for (int q = 0; q < 5; ++q)
#pragma unroll
      for (int o = 0; o < 8; ++o) sh[q][row][xs + o] = acc[q][o];
  }
  __syncthreads();

  // ---- Phase 2: vertical 11-tap blur + SSIM. 64 cols x 4 groups x 5 rows.
  const int col = tid & 63;
  const int r0 = (tid >> 6) * 5;
  float hv[5][15];
#pragma unroll
  for (int q = 0; q < 5; ++q)
#pragma unroll
    for (int i = 0; i < 15; ++i) hv[q][i] = sh[q][r0 + i][col];

  const float C1 = 6.5025f, C2 = 58.5225f;
  float lsum = 0.f;
#pragma unroll
  for (int o = 0; o < 5; ++o) {
    float mu1 = 0.f, mu2 = 0.f, e1 = 0.f, e2 = 0.f, e12 = 0.f;
#pragma unroll
    for (int t = 0; t < 11; ++t) {
      const float wt = w[t];
      mu1 = fmaf(wt, hv[0][o + t], mu1);
      mu2 = fmaf(wt, hv[1][o + t], mu2);
      e1 = fmaf(wt, hv[2][o + t], e1);
      e2 = fmaf(wt, hv[3][o + t], e2);
      e12 = fmaf(wt, hv[4][o + t], e12);
    }
    const float m12 = mu1 * mu2;
    const float m1s = mu1 * mu1;
    const float m2s = mu2 * mu2;
    const float num = (2.f * m12 + C1) * (2.f * (e12 - m12) + C2);
    const float den = (m1s + m2s + C1) * ((e1 - m1s) + (e2 - m2s) + C2);
    const int y = y0 + r0 + o;
    lsum += (y < IMH) ? (num / den) : 0.f;
  }

  // Block reduction -> deterministic per-block partial.
#pragma unroll
  for (int off = 32; off > 0; off >>= 1) lsum += __shfl_down(lsum, off, 64);
  if ((tid & 63) == 0) swsum[tid >> 6] = lsum;
  __syncthreads();
  if (tid == 0) partial[bid] = swsum[0] + swsum[1] + swsum[2] + swsum[3];
}

__global__ void ssim_reduce(const float* __restrict__ partial,
                            float* __restrict__ out) {
  const int nv = NBLOCKS / 4;  // 4992 float4
  double s = 0.0;
  for (int i = threadIdx.x; i < nv; i += 256) {
    float4 v = ((const float4*)partial)[i];
    s += (double)v.x + (double)v.y + (double)v.z + (double)v.w;
  }
#pragma unroll
  for (int off = 32; off > 0; off >>= 1) s += __shfl_down(s, off, 64);
  __shared__ double sd[4];
  if ((threadIdx.x & 63) == 0) sd[threadIdx.x >> 6] = s;
  __syncthreads();
  if (threadIdx.x == 0) {
    double npix = (double)NPLANES * (double)IMW * (double)IMH;
    out[0] = (float)(1.0 - (sd[0] + sd[1] + sd[2] + sd[3]) / npix);
  }
}

extern "C" void kernel_launch(void* const* d_in, const int* in_sizes, int n_in,
                              void* d_out, int out_size, void* d_ws, size_t ws_size,
                              hipStream_t stream) {
  (void)in_sizes; (void)n_in; (void)out_size; (void)ws_size;
  const float* gen = (const float*)d_in[0];
  const float* ref = (const float*)d_in[1];
  float* partial = (float*)d_ws;  // NBLOCKS floats; every slot written each call
  ssim_main<<<NBLOCKS, 256, 0, stream>>>(gen, ref, partial);
  ssim_reduce<<<1, 256, 0, stream>>>(partial, (float*)d_out);
}